// Round 4
// baseline (330.752 us; speedup 1.0000x reference)
//
#include <hip/hip_runtime.h>
#include <hip/hip_bf16.h>

#define NROW 4096
#define D0   1024
#define DH1  512
#define DH2  256
#define DLAT 128
#define SLOPE 0.01f

typedef float f32x4 __attribute__((ext_vector_type(4)));
typedef __bf16 bf16x8 __attribute__((ext_vector_type(8)));
typedef short short8 __attribute__((ext_vector_type(8)));

#define WAITV(N) asm volatile("s_waitcnt vmcnt(" #N ")" ::: "memory")
#define BARRIER() do { __builtin_amdgcn_s_barrier(); __builtin_amdgcn_sched_barrier(0); } while (0)

// ---- async global->LDS 16B (wave-uniform base + lane*16 dest) ----
__device__ __forceinline__ void gload_lds16(const void* gp, void* lp) {
    __builtin_amdgcn_global_load_lds(
        (const __attribute__((address_space(1))) void*)(unsigned long long)gp,
        (__attribute__((address_space(3))) void*)(unsigned int)(unsigned long long)lp,
        16, 0, 0);
}

// Stage a 128x32 bf16 tile into LDS [128][32] shorts with k-slot swizzle
// (stored slot t holds source slot t ^ ((row>>1)&3); LDS dest linear in lane).
__device__ __forceinline__ void stage_tile(const __hip_bfloat16* __restrict__ src,
                                           int row0, int ldK, int k0,
                                           short* lds, int wave, int lane) {
#pragma unroll
    for (int i = 0; i < 2; ++i) {
        int lr = wave * 32 + i * 16 + (lane >> 2);
        int t  = lane & 3;
        int s  = t ^ ((lr >> 1) & 3);
        const __hip_bfloat16* gp = src + (size_t)(row0 + lr) * ldK + k0 + s * 8;
        short* lp = lds + lr * 32 + t * 8;            // wave base + lane*16B
        gload_lds16((const void*)gp, (void*)lp);
    }
}

// 64-row variant (one gload per wave)
__device__ __forceinline__ void stage_tile64(const __hip_bfloat16* __restrict__ src,
                                             int row0, int ldK, int k0,
                                             short* lds, int wave, int lane) {
    int lr = wave * 16 + (lane >> 2);
    int t  = lane & 3;
    int s  = t ^ ((lr >> 1) & 3);
    const __hip_bfloat16* gp = src + (size_t)(row0 + lr) * ldK + k0 + s * 8;
    short* lp = lds + lr * 32 + t * 8;
    gload_lds16((const void*)gp, (void*)lp);
}

__device__ __forceinline__ bf16x8 read_frag(const short* lds, int row, int kslot) {
    int pos = kslot ^ ((row >> 1) & 3);
    short8 v = *reinterpret_cast<const short8*>(lds + row * 32 + pos * 8);
    union { short8 s; bf16x8 b; } u; u.s = v; return u.b;
}

// ---- split-precision GEMM: C = lrelu(A @ W^T + b), BM=128 BN=64, D=2 ----
// 3-MFMA split: ah*bh + ah*bl + al*bh (residual ~2^-18 relative).
// Optional sumsq: atomicAdd per-row sum of squares of outputs (for latent r2).
__global__ __launch_bounds__(256) void gemm_lrelu(
    const __hip_bfloat16* __restrict__ Ah, const __hip_bfloat16* __restrict__ Al,
    const __hip_bfloat16* __restrict__ Wh, const __hip_bfloat16* __restrict__ Wl,
    const float* __restrict__ bias,
    float* __restrict__ Cf, __hip_bfloat16* __restrict__ Ch, __hip_bfloat16* __restrict__ Cl,
    float* __restrict__ sumsq, int N, int K)
{
    __shared__ short sAh[2][128 * 32];
    __shared__ short sAl[2][128 * 32];
    __shared__ short sBh[2][64 * 32];
    __shared__ short sBl[2][64 * 32];
    const int tid = threadIdx.x, lane = tid & 63, wave = tid >> 6;
    const int wm = wave >> 1, wn = wave & 1;
    const int bm = blockIdx.x, bn = blockIdx.y;
    const int nk = K >> 5;

    f32x4 acc[4][2] = {};

    auto stage_all = [&](int buf, int ks) {   // 6 gloads per wave
        stage_tile  (Ah, bm * 128, K, ks * 32, sAh[buf], wave, lane);
        stage_tile  (Al, bm * 128, K, ks * 32, sAl[buf], wave, lane);
        stage_tile64(Wh, bn * 64,  K, ks * 32, sBh[buf], wave, lane);
        stage_tile64(Wl, bn * 64,  K, ks * 32, sBl[buf], wave, lane);
    };

    stage_all(0, 0);
#pragma unroll 1
    for (int ks = 0; ks < nk; ++ks) {
        WAITV(0);      // my step-ks loads done (issued one full compute-phase ago)
        BARRIER();     // all waves' loads done; prior-step reads consumed pre-barrier
        if (ks + 1 < nk) stage_all((ks + 1) & 1, ks + 1);
        const int cur = ks & 1;
        bf16x8 ah[4], al[4], bh[2], bl[2];
#pragma unroll
        for (int m = 0; m < 4; ++m) {
            int r = wm * 64 + m * 16 + (lane & 15);
            ah[m] = read_frag(sAh[cur], r, lane >> 4);
            al[m] = read_frag(sAl[cur], r, lane >> 4);
        }
#pragma unroll
        for (int n = 0; n < 2; ++n) {
            int r = wn * 32 + n * 16 + (lane & 15);
            bh[n] = read_frag(sBh[cur], r, lane >> 4);
            bl[n] = read_frag(sBl[cur], r, lane >> 4);
        }
#pragma unroll
        for (int m = 0; m < 4; ++m)
#pragma unroll
            for (int n = 0; n < 2; ++n) {
                acc[m][n] = __builtin_amdgcn_mfma_f32_16x16x32_bf16(ah[m], bh[n], acc[m][n], 0, 0, 0);
                acc[m][n] = __builtin_amdgcn_mfma_f32_16x16x32_bf16(ah[m], bl[n], acc[m][n], 0, 0, 0);
                acc[m][n] = __builtin_amdgcn_mfma_f32_16x16x32_bf16(al[m], bh[n], acc[m][n], 0, 0, 0);
            }
    }

    float bcol[2];
#pragma unroll
    for (int n = 0; n < 2; ++n) bcol[n] = bias[bn * 64 + wn * 32 + n * 16 + (lane & 15)];

    // bias + lrelu in place, then store
#pragma unroll
    for (int m = 0; m < 4; ++m)
#pragma unroll
        for (int n = 0; n < 2; ++n)
#pragma unroll
            for (int j = 0; j < 4; ++j) {
                float v = acc[m][n][j] + bcol[n];
                acc[m][n][j] = v >= 0.f ? v : SLOPE * v;
            }
#pragma unroll
    for (int m = 0; m < 4; ++m)
#pragma unroll
        for (int n = 0; n < 2; ++n)
#pragma unroll
            for (int j = 0; j < 4; ++j) {
                int grow = bm * 128 + wm * 64 + m * 16 + (lane >> 4) * 4 + j;
                int gcol = bn * 64 + wn * 32 + n * 16 + (lane & 15);
                size_t idx = (size_t)grow * N + gcol;
                float v = acc[m][n][j];
                if (Cf) Cf[idx] = v;
                if (Ch) {
                    __hip_bfloat16 h = __float2bfloat16(v);
                    Ch[idx] = h;
                    Cl[idx] = __float2bfloat16(v - __bfloat162float(h));
                }
            }
    if (sumsq) {
#pragma unroll
        for (int m = 0; m < 4; ++m)
#pragma unroll
            for (int j = 0; j < 4; ++j) {
                float p = acc[m][0][j] * acc[m][0][j] + acc[m][1][j] * acc[m][1][j];
#pragma unroll
                for (int w = 1; w < 16; w <<= 1) p += __shfl_xor(p, w);  // 16 cols/lane-group
                if ((lane & 15) == 0) {
                    int grow = bm * 128 + wm * 64 + m * 16 + (lane >> 4) * 4 + j;
                    atomicAdd(&sumsq[grow], p);
                }
            }
    }
}

// ---- fused pairwise-distance statistics, FULL square grid, D=2 pipeline ----
// 1024 blocks (XCD-chunked). 36 steps: 0..31 G1 = x x^T, 32..35 G2 = lat lat^T.
// All ordered pairs counted once (weight 1); diagonal contributes exact 0.
__global__ __launch_bounds__(256) void pairwise_corr(
    const __hip_bfloat16* __restrict__ Xh, const __hip_bfloat16* __restrict__ Lh,
    const float* __restrict__ r1, const float* __restrict__ r2,
    double* __restrict__ stats)
{
    int bid = (blockIdx.x & 7) * 128 + (blockIdx.x >> 3);   // 1024 = 8*128 bijective
    const int bm = bid >> 5, bn = bid & 31;

    __shared__ short sA[2][128 * 32];
    __shared__ short sB[2][128 * 32];
    const int tid = threadIdx.x, lane = tid & 63, wave = tid >> 6;
    const int wm = wave >> 1, wn = wave & 1;

    f32x4 acc[4][4] = {};
    f32x4 acc2[4][4] = {};

    auto stage_step = [&](int buf, int t) {   // 4 gloads per wave
        if (t < 32) {
            stage_tile(Xh, bm * 128, D0, t * 32, sA[buf], wave, lane);
            stage_tile(Xh, bn * 128, D0, t * 32, sB[buf], wave, lane);
        } else {
            int k0 = (t - 32) * 32;
            stage_tile(Lh, bm * 128, DLAT, k0, sA[buf], wave, lane);
            stage_tile(Lh, bn * 128, DLAT, k0, sB[buf], wave, lane);
        }
    };

    stage_step(0, 0);
#pragma unroll 1
    for (int t = 0; t < 36; ++t) {
        WAITV(0);
        BARRIER();
        if (t + 1 < 36) stage_step((t + 1) & 1, t + 1);
        const int cur = t & 1;
        bf16x8 a[4], b[4];
#pragma unroll
        for (int m = 0; m < 4; ++m) a[m] = read_frag(sA[cur], wm * 64 + m * 16 + (lane & 15), lane >> 4);
#pragma unroll
        for (int n = 0; n < 4; ++n) b[n] = read_frag(sB[cur], wn * 64 + n * 16 + (lane & 15), lane >> 4);
        if (t < 32) {
#pragma unroll
            for (int m = 0; m < 4; ++m)
#pragma unroll
                for (int n = 0; n < 4; ++n)
                    acc[m][n] = __builtin_amdgcn_mfma_f32_16x16x32_bf16(a[m], b[n], acc[m][n], 0, 0, 0);
        } else {
#pragma unroll
            for (int m = 0; m < 4; ++m)
#pragma unroll
                for (int n = 0; n < 4; ++n)
                    acc2[m][n] = __builtin_amdgcn_mfma_f32_16x16x32_bf16(a[m], b[n], acc2[m][n], 0, 0, 0);
        }
    }

    float s1 = 0.f, s2 = 0.f, s11 = 0.f, s22 = 0.f, s12 = 0.f;
#pragma unroll
    for (int m = 0; m < 4; ++m)
#pragma unroll
        for (int n = 0; n < 4; ++n)
#pragma unroll
            for (int j = 0; j < 4; ++j) {
                int gi = bm * 128 + wm * 64 + m * 16 + (lane >> 4) * 4 + j;
                int gj = bn * 128 + wn * 64 + n * 16 + (lane & 15);
                float sq1 = r1[gi] + r1[gj] - 2.0f * acc[m][n][j];
                float d1v = (gi == gj || sq1 <= 0.f) ? 0.f : sqrtf(sq1);
                float sq2 = r2[gi] + r2[gj] - 2.0f * acc2[m][n][j];
                float d2v = (gi == gj || sq2 <= 0.f) ? 0.f : sqrtf(sq2);
                s1 += d1v; s2 += d2v;
                s11 += d1v * d1v; s22 += d2v * d2v; s12 += d1v * d2v;
            }

    float vals[5] = { s1, s2, s11, s22, s12 };
#pragma unroll
    for (int q = 0; q < 5; ++q)
        for (int off = 32; off; off >>= 1) vals[q] += __shfl_down(vals[q], off);

    __syncthreads();                 // done with LDS; reuse as reduce buffer
    float* red = (float*)sA;
    if (lane == 0) {
#pragma unroll
        for (int q = 0; q < 5; ++q) red[wave * 5 + q] = vals[q];
    }
    __syncthreads();
    if (tid == 0) {
#pragma unroll
        for (int q = 0; q < 5; ++q) {
            double tt = (double)red[q] + (double)red[5 + q] + (double)red[10 + q] + (double)red[15 + q];
            atomicAdd(&stats[q], tt);
        }
    }
}

// ---- fused hi/lo split for x + all 6 weights; also r1 = rowsumsq(x) ----
// x occupies v-units [0, 1048576): block b (b<4096) handles exactly row b.
struct SplitSeg { const float* src; __hip_bfloat16* hi; __hip_bfloat16* lo; };
struct SplitArgs { SplitSeg s[7]; unsigned cum4[8]; };

__global__ void split_many(SplitArgs A, int total4, float* __restrict__ r1) {
    int v = blockIdx.x * blockDim.x + threadIdx.x;
    if (v >= total4) return;
    int si = 0;
#pragma unroll
    for (int i = 1; i < 7; ++i) si = (v >= (int)A.cum4[i]) ? i : si;
    int local = v - (int)A.cum4[si];
    float4 f = *(const float4*)(A.s[si].src + (size_t)local * 4);
    float fv[4] = { f.x, f.y, f.z, f.w };
    __hip_bfloat16* hi = A.s[si].hi;
    __hip_bfloat16* lo = A.s[si].lo;
#pragma unroll
    for (int j = 0; j < 4; ++j) {
        __hip_bfloat16 h = __float2bfloat16(fv[j]);
        hi[local * 4 + j] = h;
        lo[local * 4 + j] = __float2bfloat16(fv[j] - __bfloat162float(h));
    }
    if (blockIdx.x < 4096) {   // pure-x block == one row of x
        float s = fv[0]*fv[0] + fv[1]*fv[1] + fv[2]*fv[2] + fv[3]*fv[3];
        for (int off = 32; off; off >>= 1) s += __shfl_down(s, off);
        __shared__ float red[4];
        int lane = threadIdx.x & 63, wave = threadIdx.x >> 6;
        if (lane == 0) red[wave] = s;
        __syncthreads();
        if (threadIdx.x == 0) r1[blockIdx.x] = red[0] + red[1] + red[2] + red[3];
    }
}

__global__ void finalize_corr(const double* __restrict__ stats, float* __restrict__ corr_out) {
    double n = (double)NROW * (double)NROW;
    double s1 = stats[0], s2 = stats[1], s11 = stats[2], s22 = stats[3], s12 = stats[4];
    double m1 = s1 / n, m2 = s2 / n;
    double cov = s12 / n - m1 * m2;                  // biased (mean)
    double v1 = (s11 - n * m1 * m1) / (n - 1.0);     // unbiased (ddof=1)
    double v2 = (s22 - n * m2 * m2) / (n - 1.0);
    corr_out[0] = (float)(cov / sqrt(v1 * v2));
}

extern "C" void kernel_launch(void* const* d_in, const int* in_sizes, int n_in,
                              void* d_out, int out_size, void* d_ws, size_t ws_size,
                              hipStream_t stream) {
    const float* x   = (const float*)d_in[0];
    const float* We1 = (const float*)d_in[1];  const float* be1 = (const float*)d_in[2];
    const float* We2 = (const float*)d_in[3];  const float* be2 = (const float*)d_in[4];
    const float* We3 = (const float*)d_in[5];  const float* be3 = (const float*)d_in[6];
    const float* Wd1 = (const float*)d_in[7];  const float* bd1 = (const float*)d_in[8];
    const float* Wd2 = (const float*)d_in[9];  const float* bd2 = (const float*)d_in[10];
    const float* Wd3 = (const float*)d_in[11]; const float* bd3 = (const float*)d_in[12];
    float* out = (float*)d_out;

    char* ws = (char*)d_ws;
    size_t off = 0;
    auto alloc = [&](size_t bytes) -> char* {
        char* p = ws + off; off += (bytes + 255) & ~(size_t)255; return p;
    };
    typedef __hip_bfloat16 bf;
    bf* xh  = (bf*)alloc((size_t)NROW * D0 * 2);   bf* xl  = (bf*)alloc((size_t)NROW * D0 * 2);
    bf* w1h = (bf*)alloc((size_t)DH1 * D0 * 2);    bf* w1l = (bf*)alloc((size_t)DH1 * D0 * 2);
    bf* w2h = (bf*)alloc((size_t)DH2 * DH1 * 2);   bf* w2l = (bf*)alloc((size_t)DH2 * DH1 * 2);
    bf* w3h = (bf*)alloc((size_t)DLAT * DH2 * 2);  bf* w3l = (bf*)alloc((size_t)DLAT * DH2 * 2);
    bf* w4h = (bf*)alloc((size_t)DH2 * DLAT * 2);  bf* w4l = (bf*)alloc((size_t)DH2 * DLAT * 2);
    bf* w5h = (bf*)alloc((size_t)DH1 * DH2 * 2);   bf* w5l = (bf*)alloc((size_t)DH1 * DH2 * 2);
    bf* w6h = (bf*)alloc((size_t)D0 * DH1 * 2);    bf* w6l = (bf*)alloc((size_t)D0 * DH1 * 2);
    bf* h1h = (bf*)alloc((size_t)NROW * DH1 * 2);  bf* h1l = (bf*)alloc((size_t)NROW * DH1 * 2);
    bf* h2h = (bf*)alloc((size_t)NROW * DH2 * 2);  bf* h2l = (bf*)alloc((size_t)NROW * DH2 * 2);
    bf* lth = (bf*)alloc((size_t)NROW * DLAT * 2); bf* ltl = (bf*)alloc((size_t)NROW * DLAT * 2);
    bf* d4h = (bf*)alloc((size_t)NROW * DH2 * 2);  bf* d4l = (bf*)alloc((size_t)NROW * DH2 * 2);
    bf* d5h = (bf*)alloc((size_t)NROW * DH1 * 2);  bf* d5l = (bf*)alloc((size_t)NROW * DH1 * 2);
    float* r1v = (float*)alloc((size_t)NROW * 4);
    float* r2v = (float*)alloc((size_t)NROW * 4);      // 16384 B, 256-aligned
    double* stats = (double*)alloc(5 * 8);             // contiguous after r2v

    // zero r2v + stats in one async memset (graph-capture safe)
    hipMemsetAsync(r2v, 0, (size_t)NROW * 4 + 256, stream);

    SplitArgs SA;
    const float* srcs[7] = { x, We1, We2, We3, Wd1, Wd2, Wd3 };
    bf* his[7] = { xh, w1h, w2h, w3h, w4h, w5h, w6h };
    bf* los[7] = { xl, w1l, w2l, w3l, w4l, w5l, w6l };
    unsigned ns[7] = { NROW * D0, DH1 * D0, DH2 * DH1, DLAT * DH2,
                       DH2 * DLAT, DH1 * DH2, D0 * DH1 };
    unsigned cum = 0;
    for (int i = 0; i < 7; ++i) {
        SA.s[i].src = srcs[i]; SA.s[i].hi = his[i]; SA.s[i].lo = los[i];
        SA.cum4[i] = cum; cum += ns[i] / 4;
    }
    SA.cum4[7] = cum;
    split_many<<<(cum + 255) / 256, 256, 0, stream>>>(SA, (int)cum, r1v);

    // encoder
    gemm_lrelu<<<dim3(NROW / 128, DH1 / 64), 256, 0, stream>>>(
        xh, xl, w1h, w1l, be1, nullptr, h1h, h1l, nullptr, DH1, D0);
    gemm_lrelu<<<dim3(NROW / 128, DH2 / 64), 256, 0, stream>>>(
        h1h, h1l, w2h, w2l, be2, nullptr, h2h, h2l, nullptr, DH2, DH1);
    gemm_lrelu<<<dim3(NROW / 128, DLAT / 64), 256, 0, stream>>>(
        h2h, h2l, w3h, w3l, be3, nullptr, lth, ltl, r2v, DLAT, DH2);
    // decoder
    gemm_lrelu<<<dim3(NROW / 128, DH2 / 64), 256, 0, stream>>>(
        lth, ltl, w4h, w4l, bd1, nullptr, d4h, d4l, nullptr, DH2, DLAT);
    gemm_lrelu<<<dim3(NROW / 128, DH1 / 64), 256, 0, stream>>>(
        d4h, d4l, w5h, w5l, bd2, nullptr, d5h, d5l, nullptr, DH1, DH2);
    gemm_lrelu<<<dim3(NROW / 128, D0 / 64), 256, 0, stream>>>(
        d5h, d5l, w6h, w6l, bd3, out, nullptr, nullptr, nullptr, D0, DH1);

    // fused pairwise-distance correlation statistics (full square: 1024 blocks)
    pairwise_corr<<<dim3(1024), 256, 0, stream>>>(xh, lth, r1v, r2v, stats);
    finalize_corr<<<1, 1, 0, stream>>>(stats, out + (size_t)NROW * D0);
}

// Round 5
// 311.530 us; speedup vs baseline: 1.0617x; 1.0617x over previous
//
#include <hip/hip_runtime.h>
#include <hip/hip_bf16.h>

#define NROW 4096
#define D0   1024
#define DH1  512
#define DH2  256
#define DLAT 128
#define SLOPE 0.01f

typedef float f32x4 __attribute__((ext_vector_type(4)));
typedef __bf16 bf16x8 __attribute__((ext_vector_type(8)));
typedef short short8 __attribute__((ext_vector_type(8)));

#define WAITV(N) asm volatile("s_waitcnt vmcnt(" #N ")" ::: "memory")
#define BARRIER() do { __builtin_amdgcn_s_barrier(); __builtin_amdgcn_sched_barrier(0); } while (0)

// ---- async global->LDS 16B (wave-uniform base + lane*16 dest) ----
__device__ __forceinline__ void gload_lds16(const void* gp, void* lp) {
    __builtin_amdgcn_global_load_lds(
        (const __attribute__((address_space(1))) void*)(unsigned long long)gp,
        (__attribute__((address_space(3))) void*)(unsigned int)(unsigned long long)lp,
        16, 0, 0);
}

__device__ __forceinline__ bf16x8 ldfrag(const short* p) {
    union { short8 s; bf16x8 b; } u;
    u.s = *reinterpret_cast<const short8*>(p);
    return u.b;
}

#define MFMA16(A, B, C) __builtin_amdgcn_mfma_f32_16x16x32_bf16((A), (B), (C), 0, 0, 0)

// ---- split-precision GEMM: C = lrelu(A @ W^T + b), BM=128 BN=64 ----
// Parity-unrolled 2-phase pipeline; all LDS offsets compile-time immediates.
// LDS arena (shorts): Ah0@0 Ah1@4096 Al0@8192 Al1@12288 | Bh0@16384 Bh1@18432 Bl0@20480 Bl1@22528
__global__ __launch_bounds__(256) void gemm_lrelu(
    const __hip_bfloat16* __restrict__ Ah, const __hip_bfloat16* __restrict__ Al,
    const __hip_bfloat16* __restrict__ Wh, const __hip_bfloat16* __restrict__ Wl,
    const float* __restrict__ bias,
    float* __restrict__ Cf, __hip_bfloat16* __restrict__ Ch, __hip_bfloat16* __restrict__ Cl,
    float* __restrict__ sumsq, int N, int K)
{
    __shared__ short smem[24576];
    const int tid = threadIdx.x, lane = tid & 63, wave = tid >> 6;
    const int wm = wave >> 1, wn = wave & 1;
    const int bm = blockIdx.x, bn = blockIdx.y;
    const int nk = K >> 5;

    // staging geometry (swizzle slot: (lr>>1)&3 invariant under lr+16)
    const int lr0 = wave * 32 + (lane >> 2), lr1 = lr0 + 16;
    const int lrW = wave * 16 + (lane >> 2);
    const int ts  = lane & 3;
    const int sa  = ts ^ ((lr0 >> 1) & 3);
    const int sw  = ts ^ ((lrW >> 1) & 3);

    const __hip_bfloat16* pAh0 = Ah + (size_t)(bm * 128 + lr0) * K + sa * 8;
    const __hip_bfloat16* pAh1 = Ah + (size_t)(bm * 128 + lr1) * K + sa * 8;
    const __hip_bfloat16* pAl0 = Al + (size_t)(bm * 128 + lr0) * K + sa * 8;
    const __hip_bfloat16* pAl1 = Al + (size_t)(bm * 128 + lr1) * K + sa * 8;
    const __hip_bfloat16* pWh0 = Wh + (size_t)(bn * 64 + lrW) * K + sw * 8;
    const __hip_bfloat16* pWl0 = Wl + (size_t)(bn * 64 + lrW) * K + sw * 8;

    short* dAh0 = smem + lr0 * 32 + ts * 8;
    short* dAh1 = smem + lr1 * 32 + ts * 8;
    short* dAl0 = smem + 8192 + lr0 * 32 + ts * 8;
    short* dAl1 = smem + 8192 + lr1 * 32 + ts * 8;
    short* dWh  = smem + 16384 + lrW * 32 + ts * 8;
    short* dWl  = smem + 20480 + lrW * 32 + ts * 8;

    // frag-read bases (pos depends only on lane; row-offsets are immediates)
    const int rA = wm * 64 + (lane & 15);
    const int rB = wn * 32 + (lane & 15);
    const int pos = (lane >> 4) ^ ((lane >> 1) & 3);
    const short* baseA = smem + rA * 32 + pos * 8;            // Ah0; Al0 at +8192
    const short* baseB = smem + 16384 + rB * 32 + pos * 8;    // Bh0; Bl0 at +4096

    f32x4 acc[4][2] = {};

    auto STAGE = [&](int ao, int bo) {   // 6 gloads; ao/bo compile-time at call sites
        gload_lds16(pAh0, dAh0 + ao); gload_lds16(pAh1, dAh1 + ao);
        gload_lds16(pAl0, dAl0 + ao); gload_lds16(pAl1, dAl1 + ao);
        gload_lds16(pWh0, dWh + bo);  gload_lds16(pWl0, dWl + bo);
        pAh0 += 32; pAh1 += 32; pAl0 += 32; pAl1 += 32; pWh0 += 32; pWl0 += 32;
    };
    auto STEP = [&](int ao, int bo) {
        bf16x8 ah[4], al[4], bh[2], bl[2];
#pragma unroll
        for (int m = 0; m < 4; ++m) {
            ah[m] = ldfrag(baseA + ao + m * 512);
            al[m] = ldfrag(baseA + 8192 + ao + m * 512);
        }
#pragma unroll
        for (int n = 0; n < 2; ++n) {
            bh[n] = ldfrag(baseB + bo + n * 512);
            bl[n] = ldfrag(baseB + 4096 + bo + n * 512);
        }
#pragma unroll
        for (int m = 0; m < 4; ++m)
#pragma unroll
            for (int n = 0; n < 2; ++n) {
                acc[m][n] = MFMA16(ah[m], bh[n], acc[m][n]);
                acc[m][n] = MFMA16(ah[m], bl[n], acc[m][n]);
                acc[m][n] = MFMA16(al[m], bh[n], acc[m][n]);
            }
    };

    STAGE(0, 0);
#pragma unroll 1
    for (int k2 = 0; k2 < (nk >> 1) - 1; ++k2) {
        WAITV(0); BARRIER();
        STAGE(4096, 2048);
        STEP(0, 0);
        WAITV(0); BARRIER();
        STAGE(0, 0);
        STEP(4096, 2048);
    }
    WAITV(0); BARRIER();
    STAGE(4096, 2048);
    STEP(0, 0);
    WAITV(0); BARRIER();
    STEP(4096, 2048);

    float bcol[2];
#pragma unroll
    for (int n = 0; n < 2; ++n) bcol[n] = bias[bn * 64 + wn * 32 + n * 16 + (lane & 15)];

#pragma unroll
    for (int m = 0; m < 4; ++m)
#pragma unroll
        for (int n = 0; n < 2; ++n)
#pragma unroll
            for (int j = 0; j < 4; ++j) {
                float v = acc[m][n][j] + bcol[n];
                acc[m][n][j] = v >= 0.f ? v : SLOPE * v;
            }
#pragma unroll
    for (int m = 0; m < 4; ++m)
#pragma unroll
        for (int n = 0; n < 2; ++n)
#pragma unroll
            for (int j = 0; j < 4; ++j) {
                int grow = bm * 128 + wm * 64 + m * 16 + (lane >> 4) * 4 + j;
                int gcol = bn * 64 + wn * 32 + n * 16 + (lane & 15);
                size_t idx = (size_t)grow * N + gcol;
                float v = acc[m][n][j];
                if (Cf) Cf[idx] = v;
                if (Ch) {
                    __hip_bfloat16 h = __float2bfloat16(v);
                    Ch[idx] = h;
                    Cl[idx] = __float2bfloat16(v - __bfloat162float(h));
                }
            }
    if (sumsq) {
#pragma unroll
        for (int m = 0; m < 4; ++m)
#pragma unroll
            for (int j = 0; j < 4; ++j) {
                float p = acc[m][0][j] * acc[m][0][j] + acc[m][1][j] * acc[m][1][j];
#pragma unroll
                for (int w = 1; w < 16; w <<= 1) p += __shfl_xor(p, w);
                if ((lane & 15) == 0) {
                    int grow = bm * 128 + wm * 64 + m * 16 + (lane >> 4) * 4 + j;
                    atomicAdd(&sumsq[grow], p);
                }
            }
    }
}

// ---- fused pairwise-distance statistics, parity-unrolled 2-phase ----
// Full square grid (1024 blocks, XCD-chunked). 32 X-steps then 4 L-steps,
// transition peeled so no branch in any loop body.
// LDS arena (shorts): A0@0 A1@4096 B0@8192 B1@12288
__global__ __launch_bounds__(256) void pairwise_corr(
    const __hip_bfloat16* __restrict__ Xh, const __hip_bfloat16* __restrict__ Lh,
    const float* __restrict__ r1, const float* __restrict__ r2,
    double* __restrict__ stats)
{
    int bid = (blockIdx.x & 7) * 128 + (blockIdx.x >> 3);   // 1024 = 8*128 bijective
    const int bm = bid >> 5, bn = bid & 31;

    __shared__ short smem[16384];
    const int tid = threadIdx.x, lane = tid & 63, wave = tid >> 6;
    const int wm = wave >> 1, wn = wave & 1;

    const int lr0 = wave * 32 + (lane >> 2), lr1 = lr0 + 16;
    const int ts  = lane & 3;
    const int sa  = ts ^ ((lr0 >> 1) & 3);

    const __hip_bfloat16* pXa0 = Xh + (size_t)(bm * 128 + lr0) * D0 + sa * 8;
    const __hip_bfloat16* pXa1 = Xh + (size_t)(bm * 128 + lr1) * D0 + sa * 8;
    const __hip_bfloat16* pXb0 = Xh + (size_t)(bn * 128 + lr0) * D0 + sa * 8;
    const __hip_bfloat16* pXb1 = Xh + (size_t)(bn * 128 + lr1) * D0 + sa * 8;

    short* dA0 = smem + lr0 * 32 + ts * 8;
    short* dA1 = smem + lr1 * 32 + ts * 8;
    short* dB0 = smem + 8192 + lr0 * 32 + ts * 8;
    short* dB1 = smem + 8192 + lr1 * 32 + ts * 8;

    const int rA = wm * 64 + (lane & 15);
    const int rB = wn * 64 + (lane & 15);
    const int pos = (lane >> 4) ^ ((lane >> 1) & 3);
    const short* baseA = smem + rA * 32 + pos * 8;           // A0; A1 at +4096
    const short* baseB = smem + 8192 + rB * 32 + pos * 8;    // B0; B1 at +4096

    f32x4 acc[4][4] = {};
    f32x4 acc2[4][4] = {};

    auto STAGEX = [&](int bo) {   // 4 gloads
        gload_lds16(pXa0, dA0 + bo); gload_lds16(pXa1, dA1 + bo);
        gload_lds16(pXb0, dB0 + bo); gload_lds16(pXb1, dB1 + bo);
        pXa0 += 32; pXa1 += 32; pXb0 += 32; pXb1 += 32;
    };
    auto STEP = [&](int bo, f32x4 (&A)[4][4]) {
        bf16x8 a[4], b[4];
#pragma unroll
        for (int m = 0; m < 4; ++m) {
            a[m] = ldfrag(baseA + bo + m * 512);
            b[m] = ldfrag(baseB + bo + m * 512);
        }
#pragma unroll
        for (int m = 0; m < 4; ++m)
#pragma unroll
            for (int n = 0; n < 4; ++n)
                A[m][n] = MFMA16(a[m], b[n], A[m][n]);
    };

    STAGEX(0);                                   // X step 0 -> buf0
#pragma unroll 1
    for (int t2 = 0; t2 < 15; ++t2) {            // X steps 0..29
        WAITV(0); BARRIER();
        STAGEX(4096);                            // odd X step -> buf1
        STEP(0, acc);
        WAITV(0); BARRIER();
        STAGEX(0);                               // even X step -> buf0
        STEP(4096, acc);
    }
    WAITV(0); BARRIER();
    STAGEX(4096);                                // X step 31 -> buf1
    STEP(0, acc);                                // t=30

    const __hip_bfloat16* qa0 = Lh + (size_t)(bm * 128 + lr0) * DLAT + sa * 8;
    const __hip_bfloat16* qa1 = Lh + (size_t)(bm * 128 + lr1) * DLAT + sa * 8;
    const __hip_bfloat16* qb0 = Lh + (size_t)(bn * 128 + lr0) * DLAT + sa * 8;
    const __hip_bfloat16* qb1 = Lh + (size_t)(bn * 128 + lr1) * DLAT + sa * 8;
    auto STAGEL = [&](int bo) {
        gload_lds16(qa0, dA0 + bo); gload_lds16(qa1, dA1 + bo);
        gload_lds16(qb0, dB0 + bo); gload_lds16(qb1, dB1 + bo);
        qa0 += 32; qa1 += 32; qb0 += 32; qb1 += 32;
    };

    WAITV(0); BARRIER();
    STAGEL(0);                                   // L0 -> buf0
    STEP(4096, acc);                             // t=31
    WAITV(0); BARRIER();
    STAGEL(4096);                                // L1 -> buf1
    STEP(0, acc2);                               // t=32
    WAITV(0); BARRIER();
    STAGEL(0);                                   // L2 -> buf0
    STEP(4096, acc2);                            // t=33
    WAITV(0); BARRIER();
    STAGEL(4096);                                // L3 -> buf1
    STEP(0, acc2);                               // t=34
    WAITV(0); BARRIER();
    STEP(4096, acc2);                            // t=35

    float s1 = 0.f, s2 = 0.f, s11 = 0.f, s22 = 0.f, s12 = 0.f;
#pragma unroll
    for (int m = 0; m < 4; ++m)
#pragma unroll
        for (int n = 0; n < 4; ++n)
#pragma unroll
            for (int j = 0; j < 4; ++j) {
                int gi = bm * 128 + wm * 64 + m * 16 + (lane >> 4) * 4 + j;
                int gj = bn * 128 + wn * 64 + n * 16 + (lane & 15);
                float sq1 = r1[gi] + r1[gj] - 2.0f * acc[m][n][j];
                float d1v = (gi == gj || sq1 <= 0.f) ? 0.f : sqrtf(sq1);
                float sq2 = r2[gi] + r2[gj] - 2.0f * acc2[m][n][j];
                float d2v = (gi == gj || sq2 <= 0.f) ? 0.f : sqrtf(sq2);
                s1 += d1v; s2 += d2v;
                s11 += d1v * d1v; s22 += d2v * d2v; s12 += d1v * d2v;
            }

    float vals[5] = { s1, s2, s11, s22, s12 };
#pragma unroll
    for (int q = 0; q < 5; ++q)
        for (int off = 32; off; off >>= 1) vals[q] += __shfl_down(vals[q], off);

    __syncthreads();                 // done with LDS; reuse as reduce buffer
    float* red = (float*)smem;
    if (lane == 0) {
#pragma unroll
        for (int q = 0; q < 5; ++q) red[wave * 5 + q] = vals[q];
    }
    __syncthreads();
    if (tid == 0) {
#pragma unroll
        for (int q = 0; q < 5; ++q) {
            double tt = (double)red[q] + (double)red[5 + q] + (double)red[10 + q] + (double)red[15 + q];
            atomicAdd(&stats[q], tt);
        }
    }
}

// ---- fused hi/lo split for x + all 6 weights; also r1 = rowsumsq(x) ----
struct SplitSeg { const float* src; __hip_bfloat16* hi; __hip_bfloat16* lo; };
struct SplitArgs { SplitSeg s[7]; unsigned cum4[8]; };

__global__ void split_many(SplitArgs A, int total4, float* __restrict__ r1) {
    int v = blockIdx.x * blockDim.x + threadIdx.x;
    if (v >= total4) return;
    int si = 0;
#pragma unroll
    for (int i = 1; i < 7; ++i) si = (v >= (int)A.cum4[i]) ? i : si;
    int local = v - (int)A.cum4[si];
    float4 f = *(const float4*)(A.s[si].src + (size_t)local * 4);
    float fv[4] = { f.x, f.y, f.z, f.w };
    __hip_bfloat16* hi = A.s[si].hi;
    __hip_bfloat16* lo = A.s[si].lo;
#pragma unroll
    for (int j = 0; j < 4; ++j) {
        __hip_bfloat16 h = __float2bfloat16(fv[j]);
        hi[local * 4 + j] = h;
        lo[local * 4 + j] = __float2bfloat16(fv[j] - __bfloat162float(h));
    }
    if (blockIdx.x < 4096) {   // pure-x block == one row of x
        float s = fv[0]*fv[0] + fv[1]*fv[1] + fv[2]*fv[2] + fv[3]*fv[3];
        for (int off = 32; off; off >>= 1) s += __shfl_down(s, off);
        __shared__ float red[4];
        int lane = threadIdx.x & 63, wave = threadIdx.x >> 6;
        if (lane == 0) red[wave] = s;
        __syncthreads();
        if (threadIdx.x == 0) r1[blockIdx.x] = red[0] + red[1] + red[2] + red[3];
    }
}

__global__ void finalize_corr(const double* __restrict__ stats, float* __restrict__ corr_out) {
    double n = (double)NROW * (double)NROW;
    double s1 = stats[0], s2 = stats[1], s11 = stats[2], s22 = stats[3], s12 = stats[4];
    double m1 = s1 / n, m2 = s2 / n;
    double cov = s12 / n - m1 * m2;                  // biased (mean)
    double v1 = (s11 - n * m1 * m1) / (n - 1.0);     // unbiased (ddof=1)
    double v2 = (s22 - n * m2 * m2) / (n - 1.0);
    corr_out[0] = (float)(cov / sqrt(v1 * v2));
}

extern "C" void kernel_launch(void* const* d_in, const int* in_sizes, int n_in,
                              void* d_out, int out_size, void* d_ws, size_t ws_size,
                              hipStream_t stream) {
    const float* x   = (const float*)d_in[0];
    const float* We1 = (const float*)d_in[1];  const float* be1 = (const float*)d_in[2];
    const float* We2 = (const float*)d_in[3];  const float* be2 = (const float*)d_in[4];
    const float* We3 = (const float*)d_in[5];  const float* be3 = (const float*)d_in[6];
    const float* Wd1 = (const float*)d_in[7];  const float* bd1 = (const float*)d_in[8];
    const float* Wd2 = (const float*)d_in[9];  const float* bd2 = (const float*)d_in[10];
    const float* Wd3 = (const float*)d_in[11]; const float* bd3 = (const float*)d_in[12];
    float* out = (float*)d_out;

    char* ws = (char*)d_ws;
    size_t off = 0;
    auto alloc = [&](size_t bytes) -> char* {
        char* p = ws + off; off += (bytes + 255) & ~(size_t)255; return p;
    };
    typedef __hip_bfloat16 bf;
    bf* xh  = (bf*)alloc((size_t)NROW * D0 * 2);   bf* xl  = (bf*)alloc((size_t)NROW * D0 * 2);
    bf* w1h = (bf*)alloc((size_t)DH1 * D0 * 2);    bf* w1l = (bf*)alloc((size_t)DH1 * D0 * 2);
    bf* w2h = (bf*)alloc((size_t)DH2 * DH1 * 2);   bf* w2l = (bf*)alloc((size_t)DH2 * DH1 * 2);
    bf* w3h = (bf*)alloc((size_t)DLAT * DH2 * 2);  bf* w3l = (bf*)alloc((size_t)DLAT * DH2 * 2);
    bf* w4h = (bf*)alloc((size_t)DH2 * DLAT * 2);  bf* w4l = (bf*)alloc((size_t)DH2 * DLAT * 2);
    bf* w5h = (bf*)alloc((size_t)DH1 * DH2 * 2);   bf* w5l = (bf*)alloc((size_t)DH1 * DH2 * 2);
    bf* w6h = (bf*)alloc((size_t)D0 * DH1 * 2);    bf* w6l = (bf*)alloc((size_t)D0 * DH1 * 2);
    bf* h1h = (bf*)alloc((size_t)NROW * DH1 * 2);  bf* h1l = (bf*)alloc((size_t)NROW * DH1 * 2);
    bf* h2h = (bf*)alloc((size_t)NROW * DH2 * 2);  bf* h2l = (bf*)alloc((size_t)NROW * DH2 * 2);
    bf* lth = (bf*)alloc((size_t)NROW * DLAT * 2); bf* ltl = (bf*)alloc((size_t)NROW * DLAT * 2);
    bf* d4h = (bf*)alloc((size_t)NROW * DH2 * 2);  bf* d4l = (bf*)alloc((size_t)NROW * DH2 * 2);
    bf* d5h = (bf*)alloc((size_t)NROW * DH1 * 2);  bf* d5l = (bf*)alloc((size_t)NROW * DH1 * 2);
    float* r1v = (float*)alloc((size_t)NROW * 4);
    float* r2v = (float*)alloc((size_t)NROW * 4);      // 16384 B, 256-aligned
    double* stats = (double*)alloc(5 * 8);             // contiguous after r2v

    // zero r2v + stats in one async memset (graph-capture safe)
    hipMemsetAsync(r2v, 0, (size_t)NROW * 4 + 256, stream);

    SplitArgs SA;
    const float* srcs[7] = { x, We1, We2, We3, Wd1, Wd2, Wd3 };
    bf* his[7] = { xh, w1h, w2h, w3h, w4h, w5h, w6h };
    bf* los[7] = { xl, w1l, w2l, w3l, w4l, w5l, w6l };
    unsigned ns[7] = { NROW * D0, DH1 * D0, DH2 * DH1, DLAT * DH2,
                       DH2 * DLAT, DH1 * DH2, D0 * DH1 };
    unsigned cum = 0;
    for (int i = 0; i < 7; ++i) {
        SA.s[i].src = srcs[i]; SA.s[i].hi = his[i]; SA.s[i].lo = los[i];
        SA.cum4[i] = cum; cum += ns[i] / 4;
    }
    SA.cum4[7] = cum;
    split_many<<<(cum + 255) / 256, 256, 0, stream>>>(SA, (int)cum, r1v);

    // encoder
    gemm_lrelu<<<dim3(NROW / 128, DH1 / 64), 256, 0, stream>>>(
        xh, xl, w1h, w1l, be1, nullptr, h1h, h1l, nullptr, DH1, D0);
    gemm_lrelu<<<dim3(NROW / 128, DH2 / 64), 256, 0, stream>>>(
        h1h, h1l, w2h, w2l, be2, nullptr, h2h, h2l, nullptr, DH2, DH1);
    gemm_lrelu<<<dim3(NROW / 128, DLAT / 64), 256, 0, stream>>>(
        h2h, h2l, w3h, w3l, be3, nullptr, lth, ltl, r2v, DLAT, DH2);
    // decoder
    gemm_lrelu<<<dim3(NROW / 128, DH2 / 64), 256, 0, stream>>>(
        lth, ltl, w4h, w4l, bd1, nullptr, d4h, d4l, nullptr, DH2, DLAT);
    gemm_lrelu<<<dim3(NROW / 128, DH1 / 64), 256, 0, stream>>>(
        d4h, d4l, w5h, w5l, bd2, nullptr, d5h, d5l, nullptr, DH1, DH2);
    gemm_lrelu<<<dim3(NROW / 128, D0 / 64), 256, 0, stream>>>(
        d5h, d5l, w6h, w6l, bd3, out, nullptr, nullptr, nullptr, D0, DH1);

    // fused pairwise-distance correlation statistics (full square: 1024 blocks)
    pairwise_corr<<<dim3(1024), 256, 0, stream>>>(xh, lth, r1v, r2v, stats);
    finalize_corr<<<1, 1, 0, stream>>>(stats, out + (size_t)NROW * D0);
}

// Round 6
// 271.648 us; speedup vs baseline: 1.2176x; 1.1468x over previous
//
#include <hip/hip_runtime.h>
#include <hip/hip_bf16.h>

#define NROW 4096
#define D0   1024
#define DH1  512
#define DH2  256
#define DLAT 128
#define SLOPE 0.01f

typedef float f32x4 __attribute__((ext_vector_type(4)));
typedef __bf16 bf16x8 __attribute__((ext_vector_type(8)));
typedef short short8 __attribute__((ext_vector_type(8)));

#define WAITV(N) asm volatile("s_waitcnt vmcnt(" #N ")" ::: "memory")
#define BARRIER() do { __builtin_amdgcn_s_barrier(); __builtin_amdgcn_sched_barrier(0); } while (0)

// ---- async global->LDS 16B (wave-uniform base + lane*16 dest) ----
__device__ __forceinline__ void gload_lds16(const void* gp, void* lp) {
    __builtin_amdgcn_global_load_lds(
        (const __attribute__((address_space(1))) void*)(unsigned long long)gp,
        (__attribute__((address_space(3))) void*)(unsigned int)(unsigned long long)lp,
        16, 0, 0);
}

__device__ __forceinline__ bf16x8 ldfrag(const short* p) {
    union { short8 s; bf16x8 b; } u;
    u.s = *reinterpret_cast<const short8*>(p);
    return u.b;
}

#define MFMA16(A, B, C) __builtin_amdgcn_mfma_f32_16x16x32_bf16((A), (B), (C), 0, 0, 0)

// ---- split-precision GEMM: C = lrelu(A @ W^T + b), BM=128 BN=64 ----
// Depth-3 counted-vmcnt pipeline (3 LDS buffer sets, WAITV(6) steady state).
// 3-MFMA split: ah*bh + ah*bl + al*bh (residual ~2^-18 relative).
// LDS arena (shorts): Ah@{0,4096,8192} Al@12288+{...} Wh@24576+{0,2048,4096} Wl@30720+{...}
__global__ __launch_bounds__(256, 2) void gemm_lrelu(
    const __hip_bfloat16* __restrict__ Ah, const __hip_bfloat16* __restrict__ Al,
    const __hip_bfloat16* __restrict__ Wh, const __hip_bfloat16* __restrict__ Wl,
    const float* __restrict__ bias,
    float* __restrict__ Cf, __hip_bfloat16* __restrict__ Ch, __hip_bfloat16* __restrict__ Cl,
    float* __restrict__ sumsq, int N, int K)
{
    __shared__ short smem[36864];
    const int tid = threadIdx.x, lane = tid & 63, wave = tid >> 6;
    const int wm = wave >> 1, wn = wave & 1;
    const int bm = blockIdx.x, bn = blockIdx.y;
    const int nk = K >> 5;

    const int lr0 = wave * 32 + (lane >> 2), lr1 = lr0 + 16;
    const int lrW = wave * 16 + (lane >> 2);
    const int ts  = lane & 3;
    const int sa  = ts ^ ((lr0 >> 1) & 3);
    const int sw  = ts ^ ((lrW >> 1) & 3);

    const __hip_bfloat16* pAh0 = Ah + (size_t)(bm * 128 + lr0) * K + sa * 8;
    const __hip_bfloat16* pAh1 = Ah + (size_t)(bm * 128 + lr1) * K + sa * 8;
    const __hip_bfloat16* pAl0 = Al + (size_t)(bm * 128 + lr0) * K + sa * 8;
    const __hip_bfloat16* pAl1 = Al + (size_t)(bm * 128 + lr1) * K + sa * 8;
    const __hip_bfloat16* pWh0 = Wh + (size_t)(bn * 64 + lrW) * K + sw * 8;
    const __hip_bfloat16* pWl0 = Wl + (size_t)(bn * 64 + lrW) * K + sw * 8;

    short* dAh0 = smem + lr0 * 32 + ts * 8;
    short* dAh1 = smem + lr1 * 32 + ts * 8;
    short* dAl0 = smem + 12288 + lr0 * 32 + ts * 8;
    short* dAl1 = smem + 12288 + lr1 * 32 + ts * 8;
    short* dWh  = smem + 24576 + lrW * 32 + ts * 8;
    short* dWl  = smem + 30720 + lrW * 32 + ts * 8;

    const int rA = wm * 64 + (lane & 15);
    const int rB = wn * 32 + (lane & 15);
    const int pos = (lane >> 4) ^ ((lane >> 1) & 3);
    const short* baseA = smem + rA * 32 + pos * 8;            // Ah; Al at +12288
    const short* baseB = smem + 24576 + rB * 32 + pos * 8;    // Wh; Wl at +6144

    f32x4 acc[4][2] = {};

    auto STAGE = [&](int oA) {   // 6 gloads; oW = oA>>1
        int oW = oA >> 1;
        gload_lds16(pAh0, dAh0 + oA); gload_lds16(pAh1, dAh1 + oA);
        gload_lds16(pAl0, dAl0 + oA); gload_lds16(pAl1, dAl1 + oA);
        gload_lds16(pWh0, dWh + oW);  gload_lds16(pWl0, dWl + oW);
        pAh0 += 32; pAh1 += 32; pAl0 += 32; pAl1 += 32; pWh0 += 32; pWl0 += 32;
    };
    auto STEP = [&](int oA) {
        int oW = oA >> 1;
        bf16x8 ah[4], al[4], bh[2], bl[2];
#pragma unroll
        for (int m = 0; m < 4; ++m) {
            ah[m] = ldfrag(baseA + oA + m * 512);
            al[m] = ldfrag(baseA + 12288 + oA + m * 512);
        }
#pragma unroll
        for (int n = 0; n < 2; ++n) {
            bh[n] = ldfrag(baseB + oW + n * 512);
            bl[n] = ldfrag(baseB + 6144 + oW + n * 512);
        }
#pragma unroll
        for (int m = 0; m < 4; ++m)
#pragma unroll
            for (int n = 0; n < 2; ++n) {
                acc[m][n] = MFMA16(ah[m], bh[n], acc[m][n]);
                acc[m][n] = MFMA16(ah[m], bl[n], acc[m][n]);
                acc[m][n] = MFMA16(al[m], bh[n], acc[m][n]);
            }
    };

    STAGE(0); STAGE(4096);
    int oc = 0;
#pragma unroll 1
    for (int k = 0; k < nk - 1; ++k) {
        WAITV(6);     // step-k loads landed (issued 2 compute-phases ago)
        BARRIER();
        int o2 = (oc == 0) ? 8192 : oc - 4096;   // offset of step k+2
        if (k + 2 < nk) STAGE(o2);
        STEP(oc);
        oc = (oc == 8192) ? 0 : oc + 4096;
    }
    WAITV(0); BARRIER();
    STEP(oc);

    float bcol[2];
#pragma unroll
    for (int n = 0; n < 2; ++n) bcol[n] = bias[bn * 64 + wn * 32 + n * 16 + (lane & 15)];

#pragma unroll
    for (int m = 0; m < 4; ++m)
#pragma unroll
        for (int n = 0; n < 2; ++n)
#pragma unroll
            for (int j = 0; j < 4; ++j) {
                float v = acc[m][n][j] + bcol[n];
                acc[m][n][j] = v >= 0.f ? v : SLOPE * v;
            }
#pragma unroll
    for (int m = 0; m < 4; ++m)
#pragma unroll
        for (int n = 0; n < 2; ++n)
#pragma unroll
            for (int j = 0; j < 4; ++j) {
                int grow = bm * 128 + wm * 64 + m * 16 + (lane >> 4) * 4 + j;
                int gcol = bn * 64 + wn * 32 + n * 16 + (lane & 15);
                size_t idx = (size_t)grow * N + gcol;
                float v = acc[m][n][j];
                if (Cf) Cf[idx] = v;
                if (Ch) {
                    __hip_bfloat16 h = __float2bfloat16(v);
                    Ch[idx] = h;
                    Cl[idx] = __float2bfloat16(v - __bfloat162float(h));
                }
            }
    if (sumsq) {
#pragma unroll
        for (int m = 0; m < 4; ++m)
#pragma unroll
            for (int j = 0; j < 4; ++j) {
                float p = acc[m][0][j] * acc[m][0][j] + acc[m][1][j] * acc[m][1][j];
#pragma unroll
                for (int w = 1; w < 16; w <<= 1) p += __shfl_xor(p, w);
                if ((lane & 15) == 0) {
                    int grow = bm * 128 + wm * 64 + m * 16 + (lane >> 4) * 4 + j;
                    atomicAdd(&sumsq[grow], p);
                }
            }
    }
}

// ---- fused pairwise-distance statistics: 8 waves, depth-2-ahead, 3 buffers ----
// Full square grid (1024 blocks, XCD-chunked). 36 steps: 0..31 G1 = x x^T,
// 32..35 G2 = latent latent^T. Per-wave tile 64x32 -> acc 32 + acc2 32 regs.
// LDS (shorts): A@{0,4096,8192} B@12288+{0,4096,8192} = 48 KB.
__global__ __launch_bounds__(512, 4) void pairwise_corr(
    const __hip_bfloat16* __restrict__ Xh, const __hip_bfloat16* __restrict__ Lh,
    const float* __restrict__ r1, const float* __restrict__ r2,
    double* __restrict__ stats)
{
    int bid = (blockIdx.x & 7) * 128 + (blockIdx.x >> 3);   // 1024 = 8*128 bijective
    const int bm = bid >> 5, bn = bid & 31;

    __shared__ short smem[24576];
    const int tid = threadIdx.x, lane = tid & 63, wave = tid >> 6;
    const int wm = wave >> 2, wn = wave & 3;    // 2 x 4 wave grid, 64x32 each

    const int lr = wave * 16 + (lane >> 2);     // 8 waves cover 128 rows
    const int ts = lane & 3;
    const int sa = ts ^ ((lr >> 1) & 3);

    const __hip_bfloat16* pXa = Xh + (size_t)(bm * 128 + lr) * D0 + sa * 8;
    const __hip_bfloat16* pXb = Xh + (size_t)(bn * 128 + lr) * D0 + sa * 8;

    short* dA = smem + lr * 32 + ts * 8;
    short* dB = smem + 12288 + lr * 32 + ts * 8;

    const int pos = (lane >> 4) ^ ((lane >> 1) & 3);
    const short* baseA = smem + (wm * 64 + (lane & 15)) * 32 + pos * 8;
    const short* baseB = smem + 12288 + (wn * 32 + (lane & 15)) * 32 + pos * 8;

    f32x4 acc[4][2] = {};
    f32x4 acc2[4][2];

    auto STAGEX = [&](int o) {   // 2 gloads per wave
        gload_lds16(pXa, dA + o); gload_lds16(pXb, dB + o);
        pXa += 32; pXb += 32;
    };
    auto STEP = [&](int o, f32x4 (&A)[4][2]) {
        bf16x8 a[4], b[2];
#pragma unroll
        for (int m = 0; m < 4; ++m) a[m] = ldfrag(baseA + o + m * 512);
#pragma unroll
        for (int n = 0; n < 2; ++n) b[n] = ldfrag(baseB + o + n * 512);
#pragma unroll
        for (int m = 0; m < 4; ++m)
#pragma unroll
            for (int n = 0; n < 2; ++n)
                A[m][n] = MFMA16(a[m], b[n], A[m][n]);
    };

    STAGEX(0); STAGEX(4096);
#pragma unroll 1
    for (int t3 = 0; t3 < 10; ++t3) {            // X steps 0..29 (3-way unrolled)
        WAITV(2); BARRIER(); STAGEX(8192); STEP(0, acc);
        WAITV(2); BARRIER(); STAGEX(0);    STEP(4096, acc);
        WAITV(2); BARRIER(); STAGEX(4096); STEP(8192, acc);
    }
    // switch staging source to latent
    const __hip_bfloat16* qa = Lh + (size_t)(bm * 128 + lr) * DLAT + sa * 8;
    const __hip_bfloat16* qb = Lh + (size_t)(bn * 128 + lr) * DLAT + sa * 8;
    auto STAGEL = [&](int o) {
        gload_lds16(qa, dA + o); gload_lds16(qb, dB + o);
        qa += 32; qb += 32;
    };
#pragma unroll
    for (int m = 0; m < 4; ++m)
#pragma unroll
        for (int n = 0; n < 2; ++n)
#pragma unroll
            for (int j = 0; j < 4; ++j) acc2[m][n][j] = 0.f;

    WAITV(2); BARRIER(); STAGEL(8192); STEP(0, acc);      // t=30 (stages t=32)
    WAITV(2); BARRIER(); STAGEL(0);    STEP(4096, acc);   // t=31 (stages t=33)
    WAITV(2); BARRIER(); STAGEL(4096); STEP(8192, acc2);  // t=32 (stages t=34)
    WAITV(2); BARRIER(); STAGEL(8192); STEP(0, acc2);     // t=33 (stages t=35)
    WAITV(2); BARRIER();               STEP(4096, acc2);  // t=34
    WAITV(0); BARRIER();               STEP(8192, acc2);  // t=35

    float s1 = 0.f, s2 = 0.f, s11 = 0.f, s22 = 0.f, s12 = 0.f;
#pragma unroll
    for (int m = 0; m < 4; ++m)
#pragma unroll
        for (int n = 0; n < 2; ++n)
#pragma unroll
            for (int j = 0; j < 4; ++j) {
                int gi = bm * 128 + wm * 64 + m * 16 + (lane >> 4) * 4 + j;
                int gj = bn * 128 + wn * 32 + n * 16 + (lane & 15);
                float sq1 = r1[gi] + r1[gj] - 2.0f * acc[m][n][j];
                float d1v = (gi == gj || sq1 <= 0.f) ? 0.f : sqrtf(sq1);
                float sq2 = r2[gi] + r2[gj] - 2.0f * acc2[m][n][j];
                float d2v = (gi == gj || sq2 <= 0.f) ? 0.f : sqrtf(sq2);
                s1 += d1v; s2 += d2v;
                s11 += d1v * d1v; s22 += d2v * d2v; s12 += d1v * d2v;
            }

    float vals[5] = { s1, s2, s11, s22, s12 };
#pragma unroll
    for (int q = 0; q < 5; ++q)
        for (int off = 32; off; off >>= 1) vals[q] += __shfl_down(vals[q], off);

    __syncthreads();                 // done with LDS; reuse as reduce buffer
    float* red = (float*)smem;
    if (lane == 0) {
#pragma unroll
        for (int q = 0; q < 5; ++q) red[wave * 5 + q] = vals[q];
    }
    __syncthreads();
    if (tid == 0) {
#pragma unroll
        for (int q = 0; q < 5; ++q) {
            double tt = 0.0;
#pragma unroll
            for (int w = 0; w < 8; ++w) tt += (double)red[w * 5 + q];
            atomicAdd(&stats[q], tt);
        }
    }
}

// ---- fused hi/lo split for x + all 6 weights; also r1 = rowsumsq(x) ----
struct SplitSeg { const float* src; __hip_bfloat16* hi; __hip_bfloat16* lo; };
struct SplitArgs { SplitSeg s[7]; unsigned cum4[8]; };

__global__ void split_many(SplitArgs A, int total4, float* __restrict__ r1) {
    int v = blockIdx.x * blockDim.x + threadIdx.x;
    if (v >= total4) return;
    int si = 0;
#pragma unroll
    for (int i = 1; i < 7; ++i) si = (v >= (int)A.cum4[i]) ? i : si;
    int local = v - (int)A.cum4[si];
    float4 f = *(const float4*)(A.s[si].src + (size_t)local * 4);
    float fv[4] = { f.x, f.y, f.z, f.w };
    __hip_bfloat16* hi = A.s[si].hi;
    __hip_bfloat16* lo = A.s[si].lo;
#pragma unroll
    for (int j = 0; j < 4; ++j) {
        __hip_bfloat16 h = __float2bfloat16(fv[j]);
        hi[local * 4 + j] = h;
        lo[local * 4 + j] = __float2bfloat16(fv[j] - __bfloat162float(h));
    }
    if (blockIdx.x < 4096) {   // pure-x block == one row of x
        float s = fv[0]*fv[0] + fv[1]*fv[1] + fv[2]*fv[2] + fv[3]*fv[3];
        for (int off = 32; off; off >>= 1) s += __shfl_down(s, off);
        __shared__ float red[4];
        int lane = threadIdx.x & 63, wave = threadIdx.x >> 6;
        if (lane == 0) red[wave] = s;
        __syncthreads();
        if (threadIdx.x == 0) r1[blockIdx.x] = red[0] + red[1] + red[2] + red[3];
    }
}

__global__ void finalize_corr(const double* __restrict__ stats, float* __restrict__ corr_out) {
    double n = (double)NROW * (double)NROW;
    double s1 = stats[0], s2 = stats[1], s11 = stats[2], s22 = stats[3], s12 = stats[4];
    double m1 = s1 / n, m2 = s2 / n;
    double cov = s12 / n - m1 * m2;                  // biased (mean)
    double v1 = (s11 - n * m1 * m1) / (n - 1.0);     // unbiased (ddof=1)
    double v2 = (s22 - n * m2 * m2) / (n - 1.0);
    corr_out[0] = (float)(cov / sqrt(v1 * v2));
}

extern "C" void kernel_launch(void* const* d_in, const int* in_sizes, int n_in,
                              void* d_out, int out_size, void* d_ws, size_t ws_size,
                              hipStream_t stream) {
    const float* x   = (const float*)d_in[0];
    const float* We1 = (const float*)d_in[1];  const float* be1 = (const float*)d_in[2];
    const float* We2 = (const float*)d_in[3];  const float* be2 = (const float*)d_in[4];
    const float* We3 = (const float*)d_in[5];  const float* be3 = (const float*)d_in[6];
    const float* Wd1 = (const float*)d_in[7];  const float* bd1 = (const float*)d_in[8];
    const float* Wd2 = (const float*)d_in[9];  const float* bd2 = (const float*)d_in[10];
    const float* Wd3 = (const float*)d_in[11]; const float* bd3 = (const float*)d_in[12];
    float* out = (float*)d_out;

    char* ws = (char*)d_ws;
    size_t off = 0;
    auto alloc = [&](size_t bytes) -> char* {
        char* p = ws + off; off += (bytes + 255) & ~(size_t)255; return p;
    };
    typedef __hip_bfloat16 bf;
    bf* xh  = (bf*)alloc((size_t)NROW * D0 * 2);   bf* xl  = (bf*)alloc((size_t)NROW * D0 * 2);
    bf* w1h = (bf*)alloc((size_t)DH1 * D0 * 2);    bf* w1l = (bf*)alloc((size_t)DH1 * D0 * 2);
    bf* w2h = (bf*)alloc((size_t)DH2 * DH1 * 2);   bf* w2l = (bf*)alloc((size_t)DH2 * DH1 * 2);
    bf* w3h = (bf*)alloc((size_t)DLAT * DH2 * 2);  bf* w3l = (bf*)alloc((size_t)DLAT * DH2 * 2);
    bf* w4h = (bf*)alloc((size_t)DH2 * DLAT * 2);  bf* w4l = (bf*)alloc((size_t)DH2 * DLAT * 2);
    bf* w5h = (bf*)alloc((size_t)DH1 * DH2 * 2);   bf* w5l = (bf*)alloc((size_t)DH1 * DH2 * 2);
    bf* w6h = (bf*)alloc((size_t)D0 * DH1 * 2);    bf* w6l = (bf*)alloc((size_t)D0 * DH1 * 2);
    bf* h1h = (bf*)alloc((size_t)NROW * DH1 * 2);  bf* h1l = (bf*)alloc((size_t)NROW * DH1 * 2);
    bf* h2h = (bf*)alloc((size_t)NROW * DH2 * 2);  bf* h2l = (bf*)alloc((size_t)NROW * DH2 * 2);
    bf* lth = (bf*)alloc((size_t)NROW * DLAT * 2); bf* ltl = (bf*)alloc((size_t)NROW * DLAT * 2);
    bf* d4h = (bf*)alloc((size_t)NROW * DH2 * 2);  bf* d4l = (bf*)alloc((size_t)NROW * DH2 * 2);
    bf* d5h = (bf*)alloc((size_t)NROW * DH1 * 2);  bf* d5l = (bf*)alloc((size_t)NROW * DH1 * 2);
    float* r1v = (float*)alloc((size_t)NROW * 4);
    float* r2v = (float*)alloc((size_t)NROW * 4);      // 16384 B, 256-aligned
    double* stats = (double*)alloc(5 * 8);             // contiguous after r2v

    // zero r2v + stats in one async memset (graph-capture safe)
    hipMemsetAsync(r2v, 0, (size_t)NROW * 4 + 256, stream);

    SplitArgs SA;
    const float* srcs[7] = { x, We1, We2, We3, Wd1, Wd2, Wd3 };
    bf* his[7] = { xh, w1h, w2h, w3h, w4h, w5h, w6h };
    bf* los[7] = { xl, w1l, w2l, w3l, w4l, w5l, w6l };
    unsigned ns[7] = { NROW * D0, DH1 * D0, DH2 * DH1, DLAT * DH2,
                       DH2 * DLAT, DH1 * DH2, D0 * DH1 };
    unsigned cum = 0;
    for (int i = 0; i < 7; ++i) {
        SA.s[i].src = srcs[i]; SA.s[i].hi = his[i]; SA.s[i].lo = los[i];
        SA.cum4[i] = cum; cum += ns[i] / 4;
    }
    SA.cum4[7] = cum;
    split_many<<<(cum + 255) / 256, 256, 0, stream>>>(SA, (int)cum, r1v);

    // encoder
    gemm_lrelu<<<dim3(NROW / 128, DH1 / 64), 256, 0, stream>>>(
        xh, xl, w1h, w1l, be1, nullptr, h1h, h1l, nullptr, DH1, D0);
    gemm_lrelu<<<dim3(NROW / 128, DH2 / 64), 256, 0, stream>>>(
        h1h, h1l, w2h, w2l, be2, nullptr, h2h, h2l, nullptr, DH2, DH1);
    gemm_lrelu<<<dim3(NROW / 128, DLAT / 64), 256, 0, stream>>>(
        h2h, h2l, w3h, w3l, be3, nullptr, lth, ltl, r2v, DLAT, DH2);
    // decoder
    gemm_lrelu<<<dim3(NROW / 128, DH2 / 64), 256, 0, stream>>>(
        lth, ltl, w4h, w4l, bd1, nullptr, d4h, d4l, nullptr, DH2, DLAT);
    gemm_lrelu<<<dim3(NROW / 128, DH1 / 64), 256, 0, stream>>>(
        d4h, d4l, w5h, w5l, bd2, nullptr, d5h, d5l, nullptr, DH1, DH2);
    gemm_lrelu<<<dim3(NROW / 128, D0 / 64), 256, 0, stream>>>(
        d5h, d5l, w6h, w6l, bd3, out, nullptr, nullptr, nullptr, D0, DH1);

    // fused pairwise-distance correlation statistics (full square: 1024 blocks)
    pairwise_corr<<<dim3(1024), 512, 0, stream>>>(xh, lth, r1v, r2v, stats);
    finalize_corr<<<1, 1, 0, stream>>>(stats, out + (size_t)NROW * D0);
}